// Round 21
// baseline (98.273 us; speedup 1.0000x reference)
//
#include <hip/hip_runtime.h>
#include <hip/hip_bf16.h>

// RNN cell: out[B,N] = tanh( concat(x,hidden)[B,K] @ W^T[K,N] + b[N] )
// M=16384, N=1024, K=2048, fp32 in/out.
// r21 = r20's fused-A scheme on a 2-blocks/CU geometry:
//   BM 256 x BN 128 x BK 32, 512 threads = 8 waves (4M x 2N, 64x64/wave),
//   LDS 48 KB -> 2 independent blocks/CU (16 waves/CU, same TLP and same
//   total LDS-read traffic as r16/r20). Mechanism: the two blocks barrier
//   independently, so one block's MFMA phase covers the other's LDS/barrier
//   phase -- the cross-phase overlap in-block fences never achieved.
//   A: fp32 from x/h -> regs at tile top, cvt + swizzled ds_write at tile
//   end (fusion verified r20: killed the 25us cvt pass). B: bf16 gload_lds
//   from tiny W-cvt pass. Swizzle for 4-slot rows: slot ^ (row&3).

typedef __bf16 bf16_t;
typedef __bf16 bf16x8 __attribute__((ext_vector_type(8)));
typedef float  f32x4  __attribute__((ext_vector_type(4)));

#define M_GLOBAL 16384
#define N_GLOBAL 1024
#define K_GLOBAL 2048
#define IN_STRIDE 1024
#define NT 64            // K-tiles of 32

__device__ __forceinline__ float fast_tanh(float v) {
    float e = __expf(2.0f * v);
    return 1.0f - 2.0f * __builtin_amdgcn_rcpf(e + 1.0f);
}

// ---------------------------------------------------------------------------
// Pass 1: cvt W only (8 MB read + 4 MB write, ~3 us).
// ---------------------------------------------------------------------------
#define W_UNITS ((long long)N_GLOBAL * K_GLOBAL / 8)

__global__ __launch_bounds__(256)
void cvt_w(const float* __restrict__ W, bf16_t* __restrict__ Wb)
{
    for (long long u = (long long)blockIdx.x * 256 + threadIdx.x; u < W_UNITS;
         u += (long long)gridDim.x * 256) {
        const long long e = u * 8;
        const float4 v0 = *(const float4*)(W + e);
        const float4 v1 = *(const float4*)(W + e + 4);
        bf16x8 o;
        o[0] = (bf16_t)v0.x; o[1] = (bf16_t)v0.y;
        o[2] = (bf16_t)v0.z; o[3] = (bf16_t)v0.w;
        o[4] = (bf16_t)v1.x; o[5] = (bf16_t)v1.y;
        o[6] = (bf16_t)v1.z; o[7] = (bf16_t)v1.w;
        *(bf16x8*)(Wb + e) = o;
    }
}

// ---------------------------------------------------------------------------
// Pass 2: 256x128 tile, BK=32, 8 waves, 2 blocks/CU.
// LDS layout (elems, bf16): dbuf d at d*12288; A part [256][32] at 0,
// B part [128][32] at 8192. Rows are 64 B (4 slots of 16 B).
// Swizzle: LDS slot s of row r holds global k-slot s^(r&3); A applies it on
// the ds_write dest (reg-staged), B on the global source col (gload_lds
// writes linearly, rule 21); frag reads use slot lk^(lr&3).
// Bank check (dense-region): stage writes cover a dense 1 KB region per
// wave (16 rows x 4 slots), frag reads cover dense 1 KB (16 rows x 64 B)
// -> minimum bank cycles, no conflicts.
// Race audit (r13/r16/r20): loads for t+1 issued at top of t; VM0 at end
// drains them; cvt+ds_write lands in buf[(t+1)&1] whose last readers
// finished at the t-1 -> t barrier (WAR ok); LGKM0 before the raw barrier
// makes writes visible (RAW ok).
// ---------------------------------------------------------------------------
__device__ __forceinline__ void gload_lds16(const bf16_t* g, bf16_t* l) {
    __builtin_amdgcn_global_load_lds(
        (const __attribute__((address_space(1))) void*)g,
        (__attribute__((address_space(3))) void*)l, 16, 0, 0);
}

__global__ __launch_bounds__(512)
void gemm_2b(const float* __restrict__ x, const float* __restrict__ h,
             const bf16_t* __restrict__ Wb,
             const float* __restrict__ bias, float* __restrict__ out)
{
    __shared__ __align__(16) bf16_t lds[2 * 12288];   // 48 KB

    const int tid = threadIdx.x;
    // XCD map (r13-style): XCD x owns m-panels x*8..x*8+7 (A L2-local);
    // all 8 n-panels (Wb 4 MB total, L2-resident).
    const int xx = blockIdx.x & 7;
    const int jj = blockIdx.x >> 3;            // 0..63
    const int bm = (xx * 8 + (jj & 7)) * 256;
    const int bn = (jj >> 3) * 128;

    const int lane = tid & 63;
    const int wid  = tid >> 6;        // 0..7
    const int wm = wid >> 1;          // 0..3 (M quarter)
    const int wn = wid & 1;           // 0..1 (N half)
    const int lr = lane & 15;
    const int lk = lane >> 4;         // k-slot 0..3
    const int s3 = lr & 3;

    // staging lane geometry: 16 rows x 4 slots per wave-chunk
    const int sr16 = lane >> 2;       // 0..15
    const int q4   = lane & 3;        // k-slot
    const int arow0 = bm + wid * 16 + sr16;
    // B source (bf16, pre-swizzled col for linear gload dest):
    const bf16_t* bS = Wb + (size_t)(bn + wid * 16 + sr16) * K_GLOBAL
                          + ((q4 ^ (sr16 & 3)) * 8);
    // A LDS write dest (swizzled slot), elems within part:
    const int aWr = (wid * 16 + sr16) * 32 + ((q4 ^ (sr16 & 3)) * 8);

    // frag-read bases (elems)
    const int aRd = (wm * 64 + lr) * 32;            // + mf*512
    const int bRd = 8192 + (wn * 64 + lr) * 32;     // + nf*512
    const int sl  = ((lk ^ s3) * 8);

    f32x4 acc[4][4];
#pragma unroll
    for (int i = 0; i < 4; ++i)
#pragma unroll
        for (int j = 0; j < 4; ++j)
            acc[i][j] = (f32x4){0.f, 0.f, 0.f, 0.f};

    float4 ar[2][2];   // A staged regs: [part][2x float4]

#define LOAD_A(T) {                                                           \
    const int k0_ = (T) * 32;                                                 \
    const float* s_ = (k0_ < 1024) ? (x + k0_) : (h + (k0_ - 1024));          \
    _Pragma("unroll")                                                         \
    for (int p_ = 0; p_ < 2; ++p_) {                                          \
        const float* r_ = s_ + (size_t)(arow0 + p_ * 128) * IN_STRIDE + q4 * 8; \
        ar[p_][0] = *(const float4*)(r_);                                     \
        ar[p_][1] = *(const float4*)(r_ + 4);                                 \
    }                                                                         \
}

#define CVT_WRITE_A(D) {                                                      \
    _Pragma("unroll")                                                         \
    for (int p_ = 0; p_ < 2; ++p_) {                                          \
        bf16x8 v_;                                                            \
        v_[0] = (bf16_t)ar[p_][0].x; v_[1] = (bf16_t)ar[p_][0].y;             \
        v_[2] = (bf16_t)ar[p_][0].z; v_[3] = (bf16_t)ar[p_][0].w;             \
        v_[4] = (bf16_t)ar[p_][1].x; v_[5] = (bf16_t)ar[p_][1].y;             \
        v_[6] = (bf16_t)ar[p_][1].z; v_[7] = (bf16_t)ar[p_][1].w;             \
        *(bf16x8*)(lds + (D) * 12288 + p_ * 4096 + aWr) = v_;                 \
    }                                                                         \
}

#define STAGE_B(T, D) {                                                       \
    gload_lds16(bS + (size_t)(T) * 32,                                        \
                lds + (D) * 12288 + 8192 + wid * 512);                        \
}

#define BAR() { asm volatile("" ::: "memory");                                \
                __builtin_amdgcn_s_barrier();                                 \
                asm volatile("" ::: "memory"); }
#define VM0()   asm volatile("s_waitcnt vmcnt(0)" ::: "memory")
#define LGKM0() asm volatile("s_waitcnt lgkmcnt(0)" ::: "memory")

    // prologue: stage tile 0
    LOAD_A(0);
    STAGE_B(0, 0);
    VM0();
    CVT_WRITE_A(0);
    LGKM0();
    BAR();

    for (int t = 0; t < NT; ++t) {
        const bf16_t* lb = lds + (t & 1) * 12288;

        // issue next tile's loads at the TOP (drained at end-of-tile VM0)
        if (t + 1 < NT) { LOAD_A(t + 1); STAGE_B(t + 1, (t + 1) & 1); }

        // fence-free compute: 8 ds_read_b128 + 16 MFMA per wave
        __builtin_amdgcn_s_setprio(1);
        {
            bf16x8 bq[4];
#pragma unroll
            for (int nf = 0; nf < 4; ++nf)
                bq[nf] = *(const bf16x8*)(lb + bRd + nf * 512 + sl);
#pragma unroll
            for (int mf = 0; mf < 4; ++mf) {
                bf16x8 af = *(const bf16x8*)(lb + aRd + mf * 512 + sl);
#pragma unroll
                for (int nf = 0; nf < 4; ++nf)
                    acc[mf][nf] = __builtin_amdgcn_mfma_f32_16x16x32_bf16(
                        af, bq[nf], acc[mf][nf], 0, 0, 0);
            }
        }
        __builtin_amdgcn_s_setprio(0);

        if (t + 1 < NT) {
            VM0();                       // A regs + B gload for t+1 resident
            CVT_WRITE_A((t + 1) & 1);    // A lands in the other dbuf
            LGKM0();                     // writes visible before barrier
            BAR();
        }
    }

#undef LOAD_A
#undef CVT_WRITE_A
#undef STAGE_B
#undef BAR
#undef VM0
#undef LGKM0

    // ---- epilogue: bias + tanh, fp32 store.
    // C/D layout: col = lane&15, row = (lane>>4)*4 + reg (verified r1-r20).
    float bv[4];
#pragma unroll
    for (int nf = 0; nf < 4; ++nf)
        bv[nf] = bias[bn + wn * 64 + nf * 16 + lr];
#pragma unroll
    for (int mf = 0; mf < 4; ++mf) {
#pragma unroll
        for (int nf = 0; nf < 4; ++nf) {
            const int col = bn + wn * 64 + nf * 16 + lr;
#pragma unroll
            for (int r = 0; r < 4; ++r) {
                const int row = bm + wm * 64 + mf * 16 + lk * 4 + r;
                out[(size_t)row * N_GLOBAL + col] = fast_tanh(acc[mf][nf][r] + bv[nf]);
            }
        }
    }
}

// ---------------------------------------------------------------------------
// Fallback (ws too small): round-3 verified fused kernel (~169 us).
// ---------------------------------------------------------------------------
#define FNT 32
__global__ __launch_bounds__(256, 2)
void rnncell_fused(const float* __restrict__ x, const float* __restrict__ h,
                   const float* __restrict__ W, const float* __restrict__ bias,
                   float* __restrict__ out)
{
    __shared__ __align__(16) bf16_t As[2][128 * 64];
    __shared__ __align__(16) bf16_t Bs[2][128 * 64];

    const int tid = threadIdx.x;
    const int bid = blockIdx.x;
    const int bm = (bid >> 3) * 128;
    const int bn = (bid & 7) * 128;

    const int lane = tid & 63;
    const int wid  = tid >> 6;
    const int wr = (wid >> 1) * 64;
    const int wc = (wid & 1) * 64;
    const int lr = lane & 15;
    const int lk = lane >> 4;

    const int row0 = tid >> 3;
    const int sl0  = tid & 7;

    f32x4 acc[4][4];
#pragma unroll
    for (int i = 0; i < 4; ++i)
#pragma unroll
        for (int j = 0; j < 4; ++j)
            acc[i][j] = (f32x4){0.f, 0.f, 0.f, 0.f};

    float4 la[4][2], lb[4][2];

#define F_LOAD_A(T) do {                                                      \
    const int k0_ = (T) * 64;                                                 \
    const float* sA_ = (k0_ < 1024)                                           \
        ? (x + (size_t)bm * IN_STRIDE + k0_)                                  \
        : (h + (size_t)bm * IN_STRIDE + (k0_ - 1024));                        \
    _Pragma("unroll")                                                         \
    for (int i_ = 0; i_ < 4; ++i_) {                                          \
        const float* pa_ = sA_ + (size_t)(row0 + i_ * 32) * IN_STRIDE + sl0 * 8; \
        la[i_][0] = *(const float4*)(pa_);                                    \
        la[i_][1] = *(const float4*)(pa_ + 4);                                \
    }                                                                         \
} while (0)

#define F_LOAD_B(T) do {                                                      \
    const float* sB_ = W + (size_t)bn * K_GLOBAL + (T) * 64;                  \
    _Pragma("unroll")                                                         \
    for (int i_ = 0; i_ < 4; ++i_) {                                          \
        const float* pb_ = sB_ + (size_t)(row0 + i_ * 32) * K_GLOBAL + sl0 * 8; \
        lb[i_][0] = *(const float4*)(pb_);                                    \
        lb[i_][1] = *(const float4*)(pb_ + 4);                                \
    }                                                                         \
} while (0)

    F_LOAD_A(0);
    F_LOAD_B(0);

    for (int t = 0; t < FNT; ++t) {
        bf16_t* __restrict__ Ab = As[t & 1];
        bf16_t* __restrict__ Bb = Bs[t & 1];

#pragma unroll
        for (int i = 0; i < 4; ++i) {
            const int row = row0 + i * 32;
            const int ssl = sl0 ^ (row & 7);
            bf16x8 va;
            va[0] = (bf16_t)la[i][0].x; va[1] = (bf16_t)la[i][0].y;
            va[2] = (bf16_t)la[i][0].z; va[3] = (bf16_t)la[i][0].w;
            va[4] = (bf16_t)la[i][1].x; va[5] = (bf16_t)la[i][1].y;
            va[6] = (bf16_t)la[i][1].z; va[7] = (bf16_t)la[i][1].w;
            *(bf16x8*)(Ab + row * 64 + ssl * 8) = va;
        }
#pragma unroll
        for (int i = 0; i < 4; ++i) {
            const int row = row0 + i * 32;
            const int ssl = sl0 ^ (row & 7);
            bf16x8 vb;
            vb[0] = (bf16_t)lb[i][0].x; vb[1] = (bf16_t)lb[i][0].y;
            vb[2] = (bf16_t)lb[i][0].z; vb[3] = (bf16_t)lb[i][0].w;
            vb[4] = (bf16_t)lb[i][1].x; vb[5] = (bf16_t)lb[i][1].y;
            vb[6] = (bf16_t)lb[i][1].z; vb[7] = (bf16_t)lb[i][1].w;
            *(bf16x8*)(Bb + row * 64 + ssl * 8) = vb;
        }

        __syncthreads();

        if (t + 1 < FNT) F_LOAD_A(t + 1);

#pragma unroll
        for (int kk = 0; kk < 2; ++kk) {
            bf16x8 af[4], bfr[4];
#pragma unroll
            for (int mf = 0; mf < 4; ++mf) {
                const int row = wr + mf * 16 + lr;
                const int sl  = (kk * 4 + lk) ^ (row & 7);
                af[mf] = *(const bf16x8*)(Ab + row * 64 + sl * 8);
            }
#pragma unroll
            for (int nf = 0; nf < 4; ++nf) {
                const int row = wc + nf * 16 + lr;
                const int sl  = (kk * 4 + lk) ^ (row & 7);
                bfr[nf] = *(const bf16x8*)(Bb + row * 64 + sl * 8);
            }
#pragma unroll
            for (int mf = 0; mf < 4; ++mf)
#pragma unroll
                for (int nf = 0; nf < 4; ++nf)
                    acc[mf][nf] = __builtin_amdgcn_mfma_f32_16x16x32_bf16(
                        af[mf], bfr[nf], acc[mf][nf], 0, 0, 0);
        }

        if (t + 1 < FNT) F_LOAD_B(t + 1);
    }
#undef F_LOAD_A
#undef F_LOAD_B

    float bv[4];
#pragma unroll
    for (int nf = 0; nf < 4; ++nf)
        bv[nf] = bias[bn + wc + nf * 16 + lr];
#pragma unroll
    for (int mf = 0; mf < 4; ++mf) {
#pragma unroll
        for (int nf = 0; nf < 4; ++nf) {
            const int col = bn + wc + nf * 16 + lr;
#pragma unroll
            for (int r = 0; r < 4; ++r) {
                const int row = bm + wr + mf * 16 + lk * 4 + r;
                out[(size_t)row * N_GLOBAL + col] = fast_tanh(acc[mf][nf][r] + bv[nf]);
            }
        }
    }
}

extern "C" void kernel_launch(void* const* d_in, const int* in_sizes, int n_in,
                              void* d_out, int out_size, void* d_ws, size_t ws_size,
                              hipStream_t stream) {
    (void)in_sizes; (void)n_in; (void)out_size;
    const float* x = (const float*)d_in[0];
    const float* h = (const float*)d_in[1];
    const float* W = (const float*)d_in[2];
    const float* b = (const float*)d_in[3];
    float* out = (float*)d_out;

    const size_t need = (size_t)N_GLOBAL * K_GLOBAL * sizeof(bf16_t);  // 4 MB
    if (ws_size >= need) {
        bf16_t* Wb = (bf16_t*)d_ws;
        cvt_w<<<512, 256, 0, stream>>>(W, Wb);
        gemm_2b<<<512, 512, 0, stream>>>(x, h, Wb, b, out);
    } else {
        rnncell_fused<<<1024, 256, 0, stream>>>(x, h, W, b, out);
    }
}

// Round 22
// 85.461 us; speedup vs baseline: 1.1499x; 1.1499x over previous
//
#include <hip/hip_runtime.h>
#include <hip/hip_bf16.h>

// RNN cell: out[B,N] = tanh( concat(x,hidden)[B,K] @ W^T[K,N] + b[N] )
// M=16384, N=1024, K=2048, fp32 in/out.
// r22 = EXACT REVERT to r20 (best measured: 85.3 us total).
//   - GEMM: r16 geometry (256x256 tile, 1024 thr = 16 waves of 64x64,
//     16x16x32 MFMA, whole-tile, 1 barrier/tile, verified slot^(row&7)
//     swizzle on 128B rows, r13 XCD map) with A's fp32->bf16 cvt FUSED
//     into staging (A: fp32->regs at tile top, cvt + swizzled ds_write at
//     tile end after VM0; B: bf16 gload_lds from tiny W-cvt pass).
//   - r21's 2-block/BK=32 variant reverted (8.4M bank conflicts: 64B-row
//     swizzles alias bank-quads; only the 128B-row swizzle is verified).

typedef __bf16 bf16_t;
typedef __bf16 bf16x8 __attribute__((ext_vector_type(8)));
typedef float  f32x4  __attribute__((ext_vector_type(4)));

#define M_GLOBAL 16384
#define N_GLOBAL 1024
#define K_GLOBAL 2048
#define IN_STRIDE 1024
#define NT 32

__device__ __forceinline__ float fast_tanh(float v) {
    float e = __expf(2.0f * v);
    return 1.0f - 2.0f * __builtin_amdgcn_rcpf(e + 1.0f);
}

// ---------------------------------------------------------------------------
// Pass 1: cvt W only. 8MB read + 4MB write -> ~3 us.
// ---------------------------------------------------------------------------
#define W_UNITS ((long long)N_GLOBAL * K_GLOBAL / 8)   // 262144

__global__ __launch_bounds__(256)
void cvt_w(const float* __restrict__ W, bf16_t* __restrict__ Wb)
{
    for (long long u = (long long)blockIdx.x * 256 + threadIdx.x; u < W_UNITS;
         u += (long long)gridDim.x * 256) {
        const long long e = u * 8;
        const float4 v0 = *(const float4*)(W + e);
        const float4 v1 = *(const float4*)(W + e + 4);
        bf16x8 o;
        o[0] = (bf16_t)v0.x; o[1] = (bf16_t)v0.y;
        o[2] = (bf16_t)v0.z; o[3] = (bf16_t)v0.w;
        o[4] = (bf16_t)v1.x; o[5] = (bf16_t)v1.y;
        o[6] = (bf16_t)v1.z; o[7] = (bf16_t)v1.w;
        *(bf16x8*)(Wb + e) = o;
    }
}

// ---------------------------------------------------------------------------
// Pass 2: 256x256 whole-tile GEMM, 16 waves of 64x64 (r16 geometry).
// LDS: 2 dbuf x {A0,A1,B0,B1} 128x64 halves = 128 KB (1 block/CU).
// Swizzle: LDS slot s of row r holds k-slot s^(r&7).
//   B: source-col pre-swizzled + linear gload_lds dest (rule 21, verified).
//   A: unswizzled coalesced global load -> swizzled ds_write dest.
// Race audit: A-regs/B-gloads for t+1 issued at top of t; VM0 at end of t
// drains both; A cvt+ds_write then lands in buf[(t+1)&1] whose last readers
// finished at the t-1 -> t barrier (WAR ok); lgkmcnt(0) before the raw
// barrier makes the writes visible (RAW ok).
// ---------------------------------------------------------------------------
__device__ __forceinline__ void gload_lds16(const bf16_t* g, bf16_t* l) {
    __builtin_amdgcn_global_load_lds(
        (const __attribute__((address_space(1))) void*)g,
        (__attribute__((address_space(3))) void*)l, 16, 0, 0);
}

__global__ __launch_bounds__(1024)
void gemm_fa(const float* __restrict__ x, const float* __restrict__ h,
             const bf16_t* __restrict__ Wb,
             const float* __restrict__ bias, float* __restrict__ out)
{
    __shared__ __align__(16) bf16_t lds[2 * 32768];   // 128 KB

    const int tid = threadIdx.x;
    // r13 XCD map: 4 blocks sharing an A-panel land on one XCD.
    const int xx = blockIdx.x & 7;
    const int gg = blockIdx.x >> 3;
    const int bm = (xx * 8 + (gg & 7)) * 256;
    const int bn = (gg >> 3) * 256;

    const int lane = tid & 63;
    const int wid  = tid >> 6;        // 0..15
    const int wm = wid >> 2;          // 0..3 (M quarter)
    const int wn = wid & 3;           // 0..3 (N quarter)
    const int lr = lane & 15;
    const int lk = lane >> 4;
    const int s7 = lr & 7;

    const int srow = lane >> 3;       // 0..7 (row within wave's 8-row chunk)
    const int q8   = lane & 7;        // k-slot for staging

    // A source (fp32): part p rows bm + p*128 + wid*8 + srow, cols k0 + q8*8
    const int arow0 = bm + wid * 8 + srow;
    // B source (bf16, pre-swizzled col for linear gload dest):
    const bf16_t* bS = Wb + (size_t)(bn + wid * 8 + srow) * K_GLOBAL
                          + (q8 ^ srow) * 8;

    // A LDS write dest (swizzled slot), elems:
    const int aWr = wid * 512 + srow * 64 + (q8 ^ srow) * 8;

    // frag-read bases (elems): parts A0,A1,B0,B1 at part*8192 within dbuf.
    const int aRd = (wm >> 1) * 8192 + ((wm & 1) * 64 + lr) * 64;
    const int bRd = (2 + (wn >> 1)) * 8192 + ((wn & 1) * 64 + lr) * 64;

    f32x4 acc[4][4];
#pragma unroll
    for (int i = 0; i < 4; ++i)
#pragma unroll
        for (int j = 0; j < 4; ++j)
            acc[i][j] = (f32x4){0.f, 0.f, 0.f, 0.f};

    float4 ar[2][2];   // A staged regs: [part][2x float4]

    // issue A global loads (fp32 -> regs) for tile T
#define LOAD_A(T) {                                                           \
    const int k0_ = (T) * 64;                                                 \
    const float* s_ = (k0_ < 1024) ? (x + k0_) : (h + (k0_ - 1024));          \
    _Pragma("unroll")                                                         \
    for (int p_ = 0; p_ < 2; ++p_) {                                          \
        const float* r_ = s_ + (size_t)(arow0 + p_ * 128) * IN_STRIDE + q8 * 8; \
        ar[p_][0] = *(const float4*)(r_);                                     \
        ar[p_][1] = *(const float4*)(r_ + 4);                                 \
    }                                                                         \
}

    // cvt staged A regs and write swizzled into dbuf D
#define CVT_WRITE_A(D) {                                                      \
    _Pragma("unroll")                                                         \
    for (int p_ = 0; p_ < 2; ++p_) {                                          \
        bf16x8 v_;                                                            \
        v_[0] = (bf16_t)ar[p_][0].x; v_[1] = (bf16_t)ar[p_][0].y;             \
        v_[2] = (bf16_t)ar[p_][0].z; v_[3] = (bf16_t)ar[p_][0].w;             \
        v_[4] = (bf16_t)ar[p_][1].x; v_[5] = (bf16_t)ar[p_][1].y;             \
        v_[6] = (bf16_t)ar[p_][1].z; v_[7] = (bf16_t)ar[p_][1].w;             \
        *(bf16x8*)(lds + (D) * 32768 + p_ * 8192 + aWr) = v_;                 \
    }                                                                         \
}

    // B stage via gload_lds (linear dest, pre-swizzled source)
#define STAGE_B(T, D) {                                                       \
    _Pragma("unroll")                                                         \
    for (int p_ = 2; p_ < 4; ++p_) {                                          \
        gload_lds16(bS + (size_t)((p_ & 1) * 128) * K_GLOBAL + (T) * 64,      \
                    lds + (D) * 32768 + p_ * 8192 + wid * 512);               \
    }                                                                         \
}

#define BAR() { asm volatile("" ::: "memory");                                \
                __builtin_amdgcn_s_barrier();                                 \
                asm volatile("" ::: "memory"); }
#define VM0()   asm volatile("s_waitcnt vmcnt(0)" ::: "memory")
#define LGKM0() asm volatile("s_waitcnt lgkmcnt(0)" ::: "memory")

    // prologue: stage tile 0
    LOAD_A(0);
    STAGE_B(0, 0);
    VM0();
    CVT_WRITE_A(0);
    LGKM0();
    BAR();

    for (int t = 0; t < NT; ++t) {
        const bf16_t* lb = lds + (t & 1) * 32768;

        // issue next tile's loads at the TOP (drained at end-of-tile VM0)
        if (t + 1 < NT) { LOAD_A(t + 1); STAGE_B(t + 1, (t + 1) & 1); }

        // fence-free compute: 16 ds_read_b128 + 32 MFMA per wave
        __builtin_amdgcn_s_setprio(1);
#pragma unroll
        for (int kk = 0; kk < 2; ++kk) {
            const int sl = ((kk * 4 + lk) ^ s7) * 8;
            bf16x8 bq[4];
#pragma unroll
            for (int nf = 0; nf < 4; ++nf)
                bq[nf] = *(const bf16x8*)(lb + bRd + nf * 1024 + sl);
#pragma unroll
            for (int mf = 0; mf < 4; ++mf) {
                bf16x8 af = *(const bf16x8*)(lb + aRd + mf * 1024 + sl);
#pragma unroll
                for (int nf = 0; nf < 4; ++nf)
                    acc[mf][nf] = __builtin_amdgcn_mfma_f32_16x16x32_bf16(
                        af, bq[nf], acc[mf][nf], 0, 0, 0);
            }
        }
        __builtin_amdgcn_s_setprio(0);

        if (t + 1 < NT) {
            VM0();                       // A regs + B gloads for t+1 resident
            CVT_WRITE_A((t + 1) & 1);    // A lands in the other dbuf
            LGKM0();                     // writes visible before barrier
            BAR();
        }
    }

#undef LOAD_A
#undef CVT_WRITE_A
#undef STAGE_B
#undef BAR
#undef VM0
#undef LGKM0

    // ---- epilogue: bias + tanh, fp32 store.
    // C/D layout: col = lane&15, row = (lane>>4)*4 + reg (verified r1-r20).
    float bv[4];
#pragma unroll
    for (int nf = 0; nf < 4; ++nf)
        bv[nf] = bias[bn + wn * 64 + nf * 16 + lr];
#pragma unroll
    for (int mf = 0; mf < 4; ++mf) {
#pragma unroll
        for (int nf = 0; nf < 4; ++nf) {
            const int col = bn + wn * 64 + nf * 16 + lr;
#pragma unroll
            for (int r = 0; r < 4; ++r) {
                const int row = bm + wm * 64 + mf * 16 + lk * 4 + r;
                out[(size_t)row * N_GLOBAL + col] = fast_tanh(acc[mf][nf][r] + bv[nf]);
            }
        }
    }
}

// ---------------------------------------------------------------------------
// Fallback (ws too small): round-3 verified fused kernel (~169 us).
// ---------------------------------------------------------------------------
#define FNT 32
__global__ __launch_bounds__(256, 2)
void rnncell_fused(const float* __restrict__ x, const float* __restrict__ h,
                   const float* __restrict__ W, const float* __restrict__ bias,
                   float* __restrict__ out)
{
    __shared__ __align__(16) bf16_t As[2][128 * 64];
    __shared__ __align__(16) bf16_t Bs[2][128 * 64];

    const int tid = threadIdx.x;
    const int bid = blockIdx.x;
    const int bm = (bid >> 3) * 128;
    const int bn = (bid & 7) * 128;

    const int lane = tid & 63;
    const int wid  = tid >> 6;
    const int wr = (wid >> 1) * 64;
    const int wc = (wid & 1) * 64;
    const int lr = lane & 15;
    const int lk = lane >> 4;

    const int row0 = tid >> 3;
    const int sl0  = tid & 7;

    f32x4 acc[4][4];
#pragma unroll
    for (int i = 0; i < 4; ++i)
#pragma unroll
        for (int j = 0; j < 4; ++j)
            acc[i][j] = (f32x4){0.f, 0.f, 0.f, 0.f};

    float4 la[4][2], lb[4][2];

#define F_LOAD_A(T) do {                                                      \
    const int k0_ = (T) * 64;                                                 \
    const float* sA_ = (k0_ < 1024)                                           \
        ? (x + (size_t)bm * IN_STRIDE + k0_)                                  \
        : (h + (size_t)bm * IN_STRIDE + (k0_ - 1024));                        \
    _Pragma("unroll")                                                         \
    for (int i_ = 0; i_ < 4; ++i_) {                                          \
        const float* pa_ = sA_ + (size_t)(row0 + i_ * 32) * IN_STRIDE + sl0 * 8; \
        la[i_][0] = *(const float4*)(pa_);                                    \
        la[i_][1] = *(const float4*)(pa_ + 4);                                \
    }                                                                         \
} while (0)

#define F_LOAD_B(T) do {                                                      \
    const float* sB_ = W + (size_t)bn * K_GLOBAL + (T) * 64;                  \
    _Pragma("unroll")                                                         \
    for (int i_ = 0; i_ < 4; ++i_) {                                          \
        const float* pb_ = sB_ + (size_t)(row0 + i_ * 32) * K_GLOBAL + sl0 * 8; \
        lb[i_][0] = *(const float4*)(pb_);                                    \
        lb[i_][1] = *(const float4*)(pb_ + 4);                                \
    }                                                                         \
} while (0)

    F_LOAD_A(0);
    F_LOAD_B(0);

    for (int t = 0; t < FNT; ++t) {
        bf16_t* __restrict__ Ab = As[t & 1];
        bf16_t* __restrict__ Bb = Bs[t & 1];

#pragma unroll
        for (int i = 0; i < 4; ++i) {
            const int row = row0 + i * 32;
            const int ssl = sl0 ^ (row & 7);
            bf16x8 va;
            va[0] = (bf16_t)la[i][0].x; va[1] = (bf16_t)la[i][0].y;
            va[2] = (bf16_t)la[i][0].z; va[3] = (bf16_t)la[i][0].w;
            va[4] = (bf16_t)la[i][1].x; va[5] = (bf16_t)la[i][1].y;
            va[6] = (bf16_t)la[i][1].z; va[7] = (bf16_t)la[i][1].w;
            *(bf16x8*)(Ab + row * 64 + ssl * 8) = va;
        }
#pragma unroll
        for (int i = 0; i < 4; ++i) {
            const int row = row0 + i * 32;
            const int ssl = sl0 ^ (row & 7);
            bf16x8 vb;
            vb[0] = (bf16_t)lb[i][0].x; vb[1] = (bf16_t)lb[i][0].y;
            vb[2] = (bf16_t)lb[i][0].z; vb[3] = (bf16_t)lb[i][0].w;
            vb[4] = (bf16_t)lb[i][1].x; vb[5] = (bf16_t)lb[i][1].y;
            vb[6] = (bf16_t)lb[i][1].z; vb[7] = (bf16_t)lb[i][1].w;
            *(bf16x8*)(Bb + row * 64 + ssl * 8) = vb;
        }

        __syncthreads();

        if (t + 1 < FNT) F_LOAD_A(t + 1);

#pragma unroll
        for (int kk = 0; kk < 2; ++kk) {
            bf16x8 af[4], bfr[4];
#pragma unroll
            for (int mf = 0; mf < 4; ++mf) {
                const int row = wr + mf * 16 + lr;
                const int sl  = (kk * 4 + lk) ^ (row & 7);
                af[mf] = *(const bf16x8*)(Ab + row * 64 + sl * 8);
            }
#pragma unroll
            for (int nf = 0; nf < 4; ++nf) {
                const int row = wc + nf * 16 + lr;
                const int sl  = (kk * 4 + lk) ^ (row & 7);
                bfr[nf] = *(const bf16x8*)(Bb + row * 64 + sl * 8);
            }
#pragma unroll
            for (int mf = 0; mf < 4; ++mf)
#pragma unroll
                for (int nf = 0; nf < 4; ++nf)
                    acc[mf][nf] = __builtin_amdgcn_mfma_f32_16x16x32_bf16(
                        af[mf], bfr[nf], acc[mf][nf], 0, 0, 0);
        }

        if (t + 1 < FNT) F_LOAD_B(t + 1);
    }
#undef F_LOAD_A
#undef F_LOAD_B

    float bv[4];
#pragma unroll
    for (int nf = 0; nf < 4; ++nf)
        bv[nf] = bias[bn + wc + nf * 16 + lr];
#pragma unroll
    for (int mf = 0; mf < 4; ++mf) {
#pragma unroll
        for (int nf = 0; nf < 4; ++nf) {
            const int col = bn + wc + nf * 16 + lr;
#pragma unroll
            for (int r = 0; r < 4; ++r) {
                const int row = bm + wr + mf * 16 + lk * 4 + r;
                out[(size_t)row * N_GLOBAL + col] = fast_tanh(acc[mf][nf][r] + bv[nf]);
            }
        }
    }
}

extern "C" void kernel_launch(void* const* d_in, const int* in_sizes, int n_in,
                              void* d_out, int out_size, void* d_ws, size_t ws_size,
                              hipStream_t stream) {
    (void)in_sizes; (void)n_in; (void)out_size;
    const float* x = (const float*)d_in[0];
    const float* h = (const float*)d_in[1];
    const float* W = (const float*)d_in[2];
    const float* b = (const float*)d_in[3];
    float* out = (float*)d_out;

    const size_t need = (size_t)N_GLOBAL * K_GLOBAL * sizeof(bf16_t);  // 4 MB
    if (ws_size >= need) {
        bf16_t* Wb = (bf16_t*)d_ws;
        cvt_w<<<512, 256, 0, stream>>>(W, Wb);
        gemm_fa<<<256, 1024, 0, stream>>>(x, h, Wb, b, out);
    } else {
        rnncell_fused<<<1024, 256, 0, stream>>>(x, h, W, b, out);
    }
}